// Round 3
// baseline (484.831 us; speedup 1.0000x reference)
//
#include <hip/hip_runtime.h>

#define B_ 256
#define T_ 512
#define N_ 128

__device__ __forceinline__ float readlane_f(float v, int k) {
    return __int_as_float(__builtin_amdgcn_readlane(__float_as_int(v), k));
}

// Barrier that drains only LDS (lgkmcnt), NOT vmcnt: global emission
// prefetches stay in flight across it.
__device__ __forceinline__ void barrier_lds() {
    asm volatile("s_waitcnt lgkmcnt(0)\n\ts_barrier" ::: "memory");
}

// One chain per block, EIGHT waves per chain (256 blocks x 512 threads,
// 2 waves/SIMD). 2-D split: wave (wj,wk), wj=w>>2, wk=w&3.
//   - computes partial out[64*wj + l] summing k in [32*wk, 32*wk+32)
//   - e[k'] = exp(trans[32*wk+k'][64*wj+l]) -> 32 floats/lane, VGPR-resident
// Per step per wave: 32 readlane + 32 fma (broadcast from OWN registers),
// 1 ds_write_b32, ONE barrier, 8 conflict-free ds_read_b32.
// All 8 waves redundantly compute the full combined alpha (bitwise identical)
// so no alpha redistribution / second barrier is needed.
__global__ __launch_bounds__(512, 2) void crf_fused_kernel(
    const float* __restrict__ lp,      // [B,T,N]
    const float* __restrict__ trans,   // [N,N]
    const float* __restrict__ startt,  // [N]
    const float* __restrict__ endt,    // [N]
    const int*   __restrict__ target,  // [B,T]
    const int*   __restrict__ lengths, // [B]
    float*       __restrict__ out)     // [B]
{
    const int b   = blockIdx.x;
    const int tid = threadIdx.x;
    const int w   = tid >> 6;          // 0..7
    const int wj  = w >> 2;            // output half
    const int wk  = w & 3;             // k quarter
    const int l   = tid & 63;

    __shared__ float part[2][4][N_];   // [parity][k-quarter][j]
    __shared__ float red[16];

    const float* lpb = lp + (size_t)b * (T_ * N_);
    const int len = lengths[b];        // in [256, 512]

    // ---- e[k'] = exp(trans[32*wk+k'][64*wj+l]) : 32 VGPRs ----
    float e[32];
    {
        const float* tq = trans + (wk << 5) * N_ + (wj << 6) + l;
        #pragma unroll
        for (int k = 0; k < 32; ++k) e[k] = __expf(tq[k * N_]);
    }

    // ---- t = 0 alpha (exp domain), fully replicated in every wave ----
    float s0v = __expf(startt[l]      + lpb[l]);        // alpha[l]
    float s1v = __expf(startt[64 + l] + lpb[64 + l]);   // alpha[64+l]

    const int kbase = (wk & 1) << 5;   // readlane base in chosen component

    float Macc = 0.f;

    // emission prefetch pipeline, distance 3 (len >= 256, rows 1..3 valid)
    float cur0 = lpb[1 * N_ + l], cur1 = lpb[1 * N_ + 64 + l];
    float nA0  = lpb[2 * N_ + l], nA1  = lpb[2 * N_ + 64 + l];
    float nB0  = lpb[3 * N_ + l], nB1  = lpb[3 * N_ + 64 + l];

    for (int t = 1; t < len; ++t) {
        const int tp = min(t + 3, T_ - 1);         // clamp: always in-bounds
        float nn0 = lpb[tp * N_ + l];
        float nn1 = lpb[tp * N_ + 64 + l];

        // emission exps off the post-combine critical chain
        float eexp0 = __expf(cur0);
        float eexp1 = __expf(cur1);

        // this wave's broadcast source: component holding alpha[32wk..32wk+32)
        const float asrc = (wk & 2) ? s1v : s0v;

        // quarter contraction: 32 readlane + 32 fma, 4 independent chains
        float a0 = 0.f, a1 = 0.f, a2 = 0.f, a3 = 0.f;
        #pragma unroll
        for (int k = 0; k < 32; k += 4) {
            float x0 = readlane_f(asrc, kbase + k);
            float x1 = readlane_f(asrc, kbase + k + 1);
            float x2 = readlane_f(asrc, kbase + k + 2);
            float x3 = readlane_f(asrc, kbase + k + 3);
            a0 = fmaf(x0, e[k],     a0);
            a1 = fmaf(x1, e[k + 1], a1);
            a2 = fmaf(x2, e[k + 2], a2);
            a3 = fmaf(x3, e[k + 3], a3);
        }
        float p = (a0 + a1) + (a2 + a3);

        const int pb = t & 1;
        part[pb][wk][(wj << 6) + l] = p;
        barrier_lds();                 // ONE barrier per step

        // every wave redundantly combines all 8 partials (conflict-free reads)
        float r00 = part[pb][0][l],      r01 = part[pb][1][l];
        float r02 = part[pb][2][l],      r03 = part[pb][3][l];
        float r10 = part[pb][0][64 + l], r11 = part[pb][1][64 + l];
        float r12 = part[pb][2][64 + l], r13 = part[pb][3][64 + l];
        float s0 = (r00 + r01) + (r02 + r03);
        float s1 = (r10 + r11) + (r12 + r13);

        if ((t & 3) == 0) {            // deferred rescale (uniform everywhere)
            float sc  = readlane_f(s0, 0);
            float isc = __builtin_amdgcn_rcpf(sc);
            s0 *= isc;
            s1 *= isc;
            Macc += __logf(sc);
        }

        s0v = s0 * eexp0;
        s1v = s1 * eexp1;

        cur0 = nA0; cur1 = nA1; nA0 = nB0; nA1 = nB1; nB0 = nn0; nB1 = nn1;
    }

    // ---- log Z from wave 0's replica ----
    if (w == 0) {
        float f = s0v * __expf(endt[l]) + s1v * __expf(endt[64 + l]);
        #pragma unroll
        for (int off = 32; off > 0; off >>= 1) f += __shfl_xor(f, off);
        if (l == 0) red[0] = Macc + __logf(f);
    }

    // ---- path score (gathers), all 512 threads ----
    const int* tg = target + b * T_;
    float acc = 0.f;
    for (int t = tid; t < len; t += 512) {
        int c = tg[t];
        acc += lpb[t * N_ + c];
        if (t + 1 < len) acc += trans[c * N_ + tg[t + 1]];
    }
    #pragma unroll
    for (int off = 32; off > 0; off >>= 1) acc += __shfl_xor(acc, off);
    if (l == 0) red[8 + w] = acc;
    __syncthreads();

    if (tid == 0) {
        float sc = red[8] + red[9] + red[10] + red[11]
                 + red[12] + red[13] + red[14] + red[15];
        out[b] = sc + startt[tg[0]] + endt[tg[len - 1]] - red[0];
    }
}

extern "C" void kernel_launch(void* const* d_in, const int* in_sizes, int n_in,
                              void* d_out, int out_size, void* d_ws, size_t ws_size,
                              hipStream_t stream) {
    const float* lp     = (const float*)d_in[0];
    const float* trans  = (const float*)d_in[1];
    const float* st     = (const float*)d_in[2];
    const float* en     = (const float*)d_in[3];
    const int*   target = (const int*)d_in[4];
    const int*   lens   = (const int*)d_in[5];
    float* out = (float*)d_out;

    crf_fused_kernel<<<B_, 512, 0, stream>>>(lp, trans, st, en, target, lens, out);
}

// Round 5
// 275.469 us; speedup vs baseline: 1.7600x; 1.7600x over previous
//
#include <hip/hip_runtime.h>

#define B_ 256
#define T_ 512
#define N_ 128

typedef float v2f __attribute__((ext_vector_type(2)));

__device__ __forceinline__ float readlane_f(float v, int k) {
    return __int_as_float(__builtin_amdgcn_readlane(__float_as_int(v), k));
}

// Barrier that drains only LDS (lgkmcnt), NOT vmcnt: global emission
// prefetches stay in flight across it.
__device__ __forceinline__ void barrier_lds() {
    asm volatile("s_waitcnt lgkmcnt(0)\n\ts_barrier" ::: "memory");
}

// One chain per block, FOUR waves (256 blocks x 256 threads, 1 wave/SIMD).
// Wave w owns k-quarter [32w, 32w+32):
//   - produces partials for ALL j (j=l packed with j=64+l, v_pk_fma)
//   - after the barrier, combines ONLY its own j-quarter [32w, 32w+32)
//     (4 pipelined ds_read_b32, 2-way bank aliasing = free), which is
//     EXACTLY the broadcast set it needs next step -> readlane from own
//     lanes 0..31. No shfl, no redistribution, ONE barrier per step.
// Rescale proxy: all waves read the same LDS word part[pb][0][0].x (any
// uniform positive scale is valid; log absorbed into Macc, identical in
// every wave).
__global__ __launch_bounds__(256, 1) void crf_fused_kernel(
    const float* __restrict__ lp,      // [B,T,N]
    const float* __restrict__ trans,   // [N,N]
    const float* __restrict__ startt,  // [N]
    const float* __restrict__ endt,    // [N]
    const int*   __restrict__ target,  // [B,T]
    const int*   __restrict__ lengths, // [B]
    float*       __restrict__ out)     // [B]
{
    const int b   = blockIdx.x;
    const int tid = threadIdx.x;
    const int w   = tid >> 6;          // wave 0..3 = k-quarter & j-quarter
    const int l   = tid & 63;
    const int lq  = l & 31;            // quarter-local index (upper dup)

    __shared__ v2f  part[2][4][64];    // [parity][k-quarter][idx] -> (j=idx, j=64+idx)
    __shared__ float red[8];

    const float* lpb = lp + (size_t)b * (T_ * N_);
    const int len = lengths[b];        // in [256, 512]

    // ---- e2[k'] = {exp(T[32w+k'][l]), exp(T[32w+k'][64+l])} : 64 VGPRs ----
    v2f e2[32];
    {
        const float* tq = trans + (w << 5) * N_;
        #pragma unroll
        for (int k = 0; k < 32; ++k) {
            e2[k] = (v2f){ __expf(tq[k * N_ + l]),
                           __expf(tq[k * N_ + 64 + l]) };
        }
    }

    // ---- own-quarter alpha in lanes 0..31 (duplicated in upper lanes) ----
    // s (lane lq) = alpha[32w + lq]
    float s = __expf(startt[(w << 5) + lq] + lpb[(w << 5) + lq]);

    float Macc = 0.f;

    // emission prefetch, distance 3: em[t] = lpb[t*N + 32w + lq]
    const float* emb = lpb + (w << 5) + lq;
    float cur = emb[1 * N_], nA = emb[2 * N_], nB = emb[3 * N_];

    // combine-read float offset inside one parity block (layout [q][64][2]):
    // own j = 32w+lq -> idx = ((w&1)<<5)+lq, comp = w>>1
    const int fi = ((((w & 1) << 5) + lq) << 1) + (w >> 1);

    for (int t = 1; t < len; ++t) {
        const int tp = min(t + 3, T_ - 1);         // clamp: always in-bounds
        float nn = emb[tp * N_];

        // emission exp off the post-combine critical chain
        float eexp = __expf(cur);

        // quarter contraction: 32 readlane + 32 pk_fma, 4 independent chains
        v2f a0 = {0.f, 0.f}, a1 = {0.f, 0.f}, a2 = {0.f, 0.f}, a3 = {0.f, 0.f};
        #pragma unroll
        for (int k = 0; k < 32; k += 4) {
            float x0 = readlane_f(s, k);
            float x1 = readlane_f(s, k + 1);
            float x2 = readlane_f(s, k + 2);
            float x3 = readlane_f(s, k + 3);
            a0 = __builtin_elementwise_fma(e2[k],     (v2f){x0, x0}, a0);
            a1 = __builtin_elementwise_fma(e2[k + 1], (v2f){x1, x1}, a1);
            a2 = __builtin_elementwise_fma(e2[k + 2], (v2f){x2, x2}, a2);
            a3 = __builtin_elementwise_fma(e2[k + 3], (v2f){x3, x3}, a3);
        }
        v2f p = (a0 + a1) + (a2 + a3);

        const int pb = t & 1;
        part[pb][w][l] = p;            // one ds_write_b64
        barrier_lds();                 // ONE barrier per step (lgkmcnt only)

        // combine ONLY own quarter: 4 pipelined b32 reads + 3 adds
        const float* pbase = (const float*)&part[pb][0][0];
        float r0 = pbase[fi];
        float r1 = pbase[128 + fi];
        float r2 = pbase[256 + fi];
        float r3 = pbase[384 + fi];
        float sc4 = (r0 + r1) + (r2 + r3);

        if ((t & 3) == 0) {            // deferred rescale, uniform proxy
            float scp = pbase[0];      // part[pb][0][0].x, same word all waves
            float isc = __builtin_amdgcn_rcpf(scp);
            sc4 *= isc;
            Macc += __logf(scp);
        }

        s = sc4 * eexp;                // new own-quarter alpha (dup upper)

        cur = nA; nA = nB; nB = nn;
    }

    // ---- log Z: each wave reduces its own quarter ----
    {
        float f = (l < 32) ? s * __expf(endt[(w << 5) + l]) : 0.f;
        #pragma unroll
        for (int off = 32; off > 0; off >>= 1) f += __shfl_xor(f, off);
        if (l == 0) red[w] = f;
    }

    // ---- path score (gathers), all 256 threads ----
    const int* tg = target + b * T_;
    float acc = 0.f;
    for (int t = tid; t < len; t += 256) {
        int c = tg[t];
        acc += lpb[t * N_ + c];
        if (t + 1 < len) acc += trans[c * N_ + tg[t + 1]];
    }
    #pragma unroll
    for (int off = 32; off > 0; off >>= 1) acc += __shfl_xor(acc, off);
    if (l == 0) red[4 + w] = acc;
    __syncthreads();

    if (tid == 0) {
        float fz = (red[0] + red[1]) + (red[2] + red[3]);
        float sc = (red[4] + red[5]) + (red[6] + red[7]);
        out[b] = sc + startt[tg[0]] + endt[tg[len - 1]] - (Macc + __logf(fz));
    }
}

extern "C" void kernel_launch(void* const* d_in, const int* in_sizes, int n_in,
                              void* d_out, int out_size, void* d_ws, size_t ws_size,
                              hipStream_t stream) {
    const float* lp     = (const float*)d_in[0];
    const float* trans  = (const float*)d_in[1];
    const float* st     = (const float*)d_in[2];
    const float* en     = (const float*)d_in[3];
    const int*   target = (const int*)d_in[4];
    const int*   lens   = (const int*)d_in[5];
    float* out = (float*)d_out;

    crf_fused_kernel<<<B_, 256, 0, stream>>>(lp, trans, st, en, target, lens, out);
}